// Round 8
// baseline (125.856 us; speedup 1.0000x reference)
//
#include <hip/hip_runtime.h>
#include <math.h>

typedef unsigned int   u32;
typedef unsigned long long u64;
typedef float nf4 __attribute__((ext_vector_type(4)));   // native vec for NT stores

#define BATCH   8
#define NDATA   8192
#define NPOINT  1024
#define NSAMPLE 32
#define CFEAT   64
#define ROWF    67            // 3 xyz + 64 feat
#define MAXCAND 128           // in-ball count per query is ~6-40; 128 is ample
#define QPB     4             // queries per block = waves per block
#define NBX     32            // x-buckets per batch
#define NBY     32            // y-buckets per batch
#define NBK     (NBX*NBY)     // 1024 (x,y) buckets per batch

// f32-element offsets of the concatenated outputs
#define OUT_IDX (BATCH*NPOINT*NSAMPLE*ROWF)              // 17563648
#define OUT_GX  (OUT_IDX + BATCH*NPOINT*NSAMPLE)         // 17825792

// f32 -> bf16 (RNE) -> f32: match the harness's bf16-rounded np reference
__device__ __forceinline__ float rnbf(float f) {
    u32 b = __float_as_uint(f);
    b += 0x7FFFu + ((b >> 16) & 1u);
    return __uint_as_float(b & 0xFFFF0000u);
}
__device__ __forceinline__ int clampidx(int v) {
    return (v < 0) ? 0 : (v > NDATA-1 ? NDATA-1 : v);
}
__device__ __forceinline__ int lanes_below(u64 m) {
    return __builtin_amdgcn_mbcnt_hi((u32)(m >> 32),
            __builtin_amdgcn_mbcnt_lo((u32)m, 0));
}
// Per-wave LDS ordering fence: all LDS in grouping_kernel is per-wave
// scratch; a wave's DS ops complete in order (lgkmcnt waits inserted by the
// compiler), so we only need to stop compiler reordering — no HW barrier.
// Empirically validated: R3/R7 ran this pattern across the suite, absmax 0.
__device__ __forceinline__ void wave_lds_fence() {
    asm volatile("" ::: "memory");
}
// monotone coord->bucket map (32 buckets over [-4.5,4.5]), shared by binning
// and query windows; clamped floor map is monotone non-decreasing, so
// bucket(p) in [bucket(lo), bucket(hi)] for any p in [lo,hi]  => covering.
__device__ __forceinline__ int cbucket(float v) {
    int c = (int)floorf((v + 4.5f) * 3.5555556f);   // 32/9
    return c < 0 ? 0 : (c > NBX-1 ? NBX-1 : c);
}
__device__ __forceinline__ int key2(float x, float y) {
    return cbucket(x)*NBY + cbucket(y);
}

// ---- K1: per-batch bucket sort by (x,y) -> interleaved float4 {x,y,z,id} ----
__global__ __launch_bounds__(1024)
void bin_kernel(const float* __restrict__ xyz,
                float4* __restrict__ wp, u32* __restrict__ wst)
{
    __shared__ u32 cnt[NBK];   // counts -> cursors
    __shared__ u32 wsum[16];   // per-wave partial sums
    const int b = blockIdx.x, tid = threadIdx.x;
    const int lane = tid & 63, wv = tid >> 6;
    const float* bx = xyz + (size_t)b * NDATA * 3;

    cnt[tid] = 0;
    __syncthreads();
    for (int p = tid; p < NDATA; p += 1024)
        atomicAdd(&cnt[key2(bx[p*3], bx[p*3+1])], 1u);
    __syncthreads();

    // exclusive scan of cnt[1024]: wave-level inclusive shfl scan + 16-wide top
    u32 v = cnt[tid];
    u32 s = v;
    #pragma unroll
    for (int off = 1; off < 64; off <<= 1) {
        u32 t = __shfl_up(s, off);
        if (lane >= off) s += t;
    }
    if (lane == 63) wsum[wv] = s;
    __syncthreads();
    if (tid < 16) {                       // sources of shfl_up stay in [0,15]
        u32 w = wsum[tid];
        #pragma unroll
        for (int off = 1; off < 16; off <<= 1) {
            u32 t = __shfl_up(w, off);
            if (tid >= off) w += t;
        }
        wsum[tid] = w;                    // inclusive over wave totals
    }
    __syncthreads();
    u32 excl = s - v + (wv ? wsum[wv-1] : 0u);
    wst[b*(NBK+1) + tid] = excl;
    cnt[tid] = excl;                      // cursor
    if (tid == 0) wst[b*(NBK+1) + NBK] = NDATA;
    __syncthreads();

    for (int p = tid; p < NDATA; p += 1024) {   // scatter (in-bucket order arbitrary)
        float x = bx[p*3], y = bx[p*3+1], z = bx[p*3+2];
        u32 pos = atomicAdd(&cnt[key2(x, y)], 1u);
        wp[(size_t)b*NDATA + pos] = make_float4(x, y, z, __uint_as_float((u32)p));
    }
}

// ---- K2: 2D-windowed scan + verified selection + pipelined NT epilogue ----
// XCD-affine block swizzle: batch = blockIdx.x % 8. MI355X round-robins
// blockIdx % 8 across the 8 XCDs, so each XCD serves exactly ONE batch;
// its working set (2 MB points + 128 KB wp + 96 KB xyz) is L2-resident.
// NT output stores keep that working set from being evicted.
__global__ __launch_bounds__(256, 8)
void grouping_kernel(const float* __restrict__ new_xyz,
                     const float* __restrict__ xyz,
                     const float* __restrict__ points,
                     const float4* __restrict__ wp, const u32* __restrict__ wst,
                     float* __restrict__ out, float T)
{
    __shared__ float cand_s[QPB][MAXCAND];   // f32 sqrt(d2)
    __shared__ int   cand_i[QPB][MAXCAND];   // point index (tie-break key)
    __shared__ int   sel[QPB][NSAMPLE];
    __shared__ __align__(16) float st[QPB][8*ROWF];  // 8-row staging (536 f32/query)

    const int tid  = threadIdx.x;
    const int wv   = tid >> 6;
    const int lane = tid & 63;
    // bijective bid -> q map: batch = bid%8 (== XCD), within-batch blk = bid/8
    const int b    = blockIdx.x & 7;          // batch == XCD
    const int q    = b * NPOINT + (blockIdx.x >> 3) * QPB + wv;

    if (lane < NSAMPLE) sel[wv][lane] = 0;    // safety net; overwritten below

    const float qx = new_xyz[q*3 + 0];
    const float qy = new_xyz[q*3 + 1];
    const float qz = new_xyz[q*3 + 2];
    const float*  bx = xyz + (size_t)b * NDATA * 3;
    const float4* cp = wp  + (size_t)b * NDATA;

    // (x,y)-window (margin 0.2005 >> any f32 rounding slop in the d2<T chain)
    const int bxlo = cbucket(__fsub_rn(qx, 0.2005f));
    const int bxhi = cbucket(__fadd_rn(qx, 0.2005f));
    const int bylo = cbucket(__fsub_rn(qy, 0.2005f));
    const int byhi = cbucket(__fadd_rn(qy, 0.2005f));
    const u32* ws = wst + b*(NBK+1);

    // per x-column, the y-window is one contiguous segment of the sorted array
    int n = 0;                                // wave-uniform candidate count
    for (int c = bxlo; c <= bxhi; ++c) {
        const u32 j0 = ws[c*NBY + bylo];
        const u32 j1 = ws[c*NBY + byhi + 1];  // (c*NBY+byhi+1) <= NBK, sentinel ok
        for (u32 jb = j0; jb < j1; jb += 64) {
            u32 j  = jb + lane;
            bool in = j < j1;
            u32 jj = in ? j : (j1 - 1u);      // safe: loop body implies j1 >= 1
            float4 vv = cp[jj];
            // exact np f32 semantics: no FMA, left-to-right sum
            float dx = __fsub_rn(vv.x, qx);
            float dy = __fsub_rn(vv.y, qy);
            float dz = __fsub_rn(vv.z, qz);
            float d2 = __fadd_rn(__fadd_rn(__fmul_rn(dx,dx), __fmul_rn(dy,dy)),
                                 __fmul_rn(dz,dz));
            bool cc = in && (d2 < T);         // == sqrtf(d2) < 0.2f (monotone)
            u64 m = __ballot(cc);
            if (cc) {
                int pos = n + lanes_below(m);
                if (pos < MAXCAND) {
                    cand_s[wv][pos] = __fsqrt_rn(d2);   // ref sorts the f32 norm
                    cand_i[wv][pos] = (int)__float_as_uint(vv.w);
                }
            }
            n += (int)__popcll(m);
        }
    }

    // ---- rare pass: argmin for empty-ball queries (R18-verified form) ----
    int mini = 0;
    if (n == 0) {
        float mind = 3.402823466e38f; int mi = 0;
        for (int k = 0; k < NDATA/64; ++k) {
            int i = (k << 6) + lane;
            float dx = __fsub_rn(bx[i*3+0], qx);
            float dy = __fsub_rn(bx[i*3+1], qy);
            float dz = __fsub_rn(bx[i*3+2], qz);
            float d2 = __fadd_rn(__fadd_rn(__fmul_rn(dx,dx), __fmul_rn(dy,dy)),
                                 __fmul_rn(dz,dz));
            if (d2 < mind) { mind = d2; mi = i; }   // strict <: lowest idx per lane
        }
        float ms = __fsqrt_rn(mind);                // np tie rule on sqrt values
        for (int off = 32; off; off >>= 1) {
            float os = __shfl_xor(ms, off);
            int   oi = __shfl_xor(mi, off);
            if (os < ms || (os == ms && oi < mi)) { ms = os; mi = oi; }
        }
        mini = mi;
    }

    wave_lds_fence();   // per-wave ordering: cand writes -> cand reads

    // ---- rank-place: (dist, point-index) lex == np stable argsort ----
    const int nj = n > MAXCAND ? MAXCAND : n;
    for (int kk = lane; kk < nj; kk += 64) {
        float sk = cand_s[wv][kk];
        int   ik = cand_i[wv][kk];
        int r = 0;
        for (int mm = 0; mm < nj; ++mm) {           // broadcast LDS reads
            float sm = cand_s[wv][mm];
            int   im = cand_i[wv][mm];
            r += (int)((sm < sk) | ((sm == sk) & (im < ik)));
        }
        if (r < NSAMPLE) sel[wv][r] = clampidx(ik);
    }
    wave_lds_fence();
    {
        const int nsel = nj < NSAMPLE ? nj : NSAMPLE;
        if (lane >= nsel && lane < NSAMPLE) {
            int pad = (nj > 0) ? sel[wv][0] : clampidx(mini);   // sorted_idx[0]
            sel[wv][lane] = pad;
        }
    }
    wave_lds_fence();

    // ---- outputs: f32 stores (nontemporal: streamed once, keep L2 for the
    //      gather working set points/wp), values pre-rounded through bf16 ----
    // idx (chunk 1)
    if (lane < NSAMPLE)
        __builtin_nontemporal_store(rnbf((float)sel[wv][lane]),
                                    &out[OUT_IDX + (size_t)q*NSAMPLE + lane]);

    // grouped_xyz (chunk 2)
    for (int e = lane; e < NSAMPLE*3; e += 64) {
        int sR = e / 3, c2 = e - sR*3;
        int is = sel[wv][sR];
        __builtin_nontemporal_store(rnbf(bx[is*3 + c2]),
                                    &out[OUT_GX + (size_t)q*(NSAMPLE*3) + e]);
    }

    // new_points (chunk 0): 4 groups of 8 rows, register-pipelined:
    //   prefetch group g+1's two float4 gathers before the store pass of g.
    //   gather: 16 lanes x float4 cover one 64-feat row (16B-aligned loads)
    //   store:  row-block contiguous & 16B-aligned in out -> nf4 NT stores
    const float* prow = points + (size_t)b * NDATA * CFEAT;
    float* onp = out + (size_t)q * (NSAMPLE*ROWF);
    const int gq = lane >> 4;     // 0..3: row within gather half
    const int lq = lane & 15;     // 0..15: float4 within the 64-feature row

    int isA = sel[wv][gq];        // group 0, rows 0..3
    int isB = sel[wv][4 + gq];    // group 0, rows 4..7
    float4 vA = *reinterpret_cast<const float4*>(prow + (size_t)isA*CFEAT + 4*lq);
    float4 vB = *reinterpret_cast<const float4*>(prow + (size_t)isB*CFEAT + 4*lq);

    for (int g = 0; g < 4; ++g) {
        {   // stage the two prefetched rows
            float* d0 = &st[wv][gq*ROWF + 3 + 4*lq];
            d0[0]=rnbf(vA.x); d0[1]=rnbf(vA.y); d0[2]=rnbf(vA.z); d0[3]=rnbf(vA.w);
            float* d1 = &st[wv][(4+gq)*ROWF + 3 + 4*lq];
            d1[0]=rnbf(vB.x); d1[1]=rnbf(vB.y); d1[2]=rnbf(vB.z); d1[3]=rnbf(vB.w);
        }
        if (lane < 24) {                           // 8 rows x 3 xyz
            int rl = lane / 3, c = lane - rl*3;
            int is = sel[wv][g*8 + rl];
            st[wv][rl*ROWF + c] = rnbf(bx[(size_t)is*3 + c]);
        }
        wave_lds_fence();                          // st writes -> st reads
        if (g < 3) {                               // prefetch next group
            isA = sel[wv][(g+1)*8 + gq];
            isB = sel[wv][(g+1)*8 + 4 + gq];
            vA = *reinterpret_cast<const float4*>(prow + (size_t)isA*CFEAT + 4*lq);
            vB = *reinterpret_cast<const float4*>(prow + (size_t)isB*CFEAT + 4*lq);
        }
        for (int i = lane; i < 134; i += 64) {     // 536 floats = 134 float4
            nf4 t = *reinterpret_cast<const nf4*>(&st[wv][4*i]);
            __builtin_nontemporal_store(t,
                reinterpret_cast<nf4*>(onp + (size_t)g*536 + 4*i));
        }
        wave_lds_fence();                          // st reads -> next overwrite
    }
}

extern "C" void kernel_launch(void* const* d_in, const int* in_sizes, int n_in,
                              void* d_out, int out_size, void* d_ws, size_t ws_size,
                              hipStream_t stream) {
    // T = smallest f32 x with sqrtf(x) >= 0.2f  =>  (d2 < T) == (sqrtf(d2) < 0.2f)
    union { u32 u; float f; } lo, hi, mid;
    lo.u = 0u; hi.f = 0.05f;
    while (hi.u - lo.u > 1u) {
        mid.u = lo.u + (hi.u - lo.u) / 2u;
        if (sqrtf(mid.f) >= 0.2f) hi.u = mid.u; else lo.u = mid.u;
    }
    float T = hi.f;

    // ws layout: wp (float4, 1 MB) | wst (u32 starts, 8*(1024+1) = ~32.8 KB)
    float4* wp  = (float4*)d_ws;
    u32*    wst = (u32*)(wp + (size_t)BATCH*NDATA);

    const float* nxz = (const float*)d_in[0];
    const float* xyz = (const float*)d_in[1];
    const float* pts = (const float*)d_in[2];

    bin_kernel<<<BATCH, 1024, 0, stream>>>(xyz, wp, wst);
    grouping_kernel<<<(BATCH*NPOINT)/QPB, 256, 0, stream>>>(
        nxz, xyz, pts, wp, wst, (float*)d_out, T);
}

// Round 9
// 122.952 us; speedup vs baseline: 1.0236x; 1.0236x over previous
//
#include <hip/hip_runtime.h>
#include <math.h>

typedef unsigned int   u32;
typedef unsigned long long u64;

#define BATCH   8
#define NDATA   8192
#define NPOINT  1024
#define NSAMPLE 32
#define CFEAT   64
#define ROWF    67            // 3 xyz + 64 feat
#define MAXCAND 128           // in-ball count per query is ~6-40; 128 is ample
#define QPB     4             // queries per block = waves per block
#define NBX     32            // x-buckets per batch
#define NBY     32            // y-buckets per batch
#define NBK     (NBX*NBY)     // 1024 (x,y) buckets per batch

// f32-element offsets of the concatenated outputs
#define OUT_IDX (BATCH*NPOINT*NSAMPLE*ROWF)              // 17563648
#define OUT_GX  (OUT_IDX + BATCH*NPOINT*NSAMPLE)         // 17825792

// f32 -> bf16 (RNE) -> f32: match the harness's bf16-rounded np reference
__device__ __forceinline__ float rnbf(float f) {
    u32 b = __float_as_uint(f);
    b += 0x7FFFu + ((b >> 16) & 1u);
    return __uint_as_float(b & 0xFFFF0000u);
}
__device__ __forceinline__ int clampidx(int v) {
    return (v < 0) ? 0 : (v > NDATA-1 ? NDATA-1 : v);
}
__device__ __forceinline__ int lanes_below(u64 m) {
    return __builtin_amdgcn_mbcnt_hi((u32)(m >> 32),
            __builtin_amdgcn_mbcnt_lo((u32)m, 0));
}
// monotone coord->bucket map (32 buckets over [-4.5,4.5]), shared by binning
// and query windows; clamped floor map is monotone non-decreasing, so
// bucket(p) in [bucket(lo), bucket(hi)] for any p in [lo,hi]  => covering.
__device__ __forceinline__ int cbucket(float v) {
    int c = (int)floorf((v + 4.5f) * 3.5555556f);   // 32/9
    return c < 0 ? 0 : (c > NBX-1 ? NBX-1 : c);
}
__device__ __forceinline__ int key2(float x, float y) {
    return cbucket(x)*NBY + cbucket(y);
}

// ---- K1: per-batch bucket sort by (x,y) -> interleaved float4 {x,y,z,id} ----
// single dispatch, 8 blocks x 1024 threads; 1024-bucket scan via two-level
// wave-shuffle scan (3 barriers instead of Hillis-Steele's 20)
__global__ __launch_bounds__(1024)
void bin_kernel(const float* __restrict__ xyz,
                float4* __restrict__ wp, u32* __restrict__ wst)
{
    __shared__ u32 cnt[NBK];   // counts -> cursors
    __shared__ u32 wsum[16];   // per-wave partial sums
    const int b = blockIdx.x, tid = threadIdx.x;
    const int lane = tid & 63, wv = tid >> 6;
    const float* bx = xyz + (size_t)b * NDATA * 3;

    cnt[tid] = 0;
    __syncthreads();
    for (int p = tid; p < NDATA; p += 1024)
        atomicAdd(&cnt[key2(bx[p*3], bx[p*3+1])], 1u);
    __syncthreads();

    // exclusive scan of cnt[1024]: wave-level inclusive shfl scan + 16-wide top
    u32 v = cnt[tid];
    u32 s = v;
    #pragma unroll
    for (int off = 1; off < 64; off <<= 1) {
        u32 t = __shfl_up(s, off);
        if (lane >= off) s += t;
    }
    if (lane == 63) wsum[wv] = s;
    __syncthreads();
    if (tid < 16) {                       // sources of shfl_up stay in [0,15]
        u32 w = wsum[tid];
        #pragma unroll
        for (int off = 1; off < 16; off <<= 1) {
            u32 t = __shfl_up(w, off);
            if (tid >= off) w += t;
        }
        wsum[tid] = w;                    // inclusive over wave totals
    }
    __syncthreads();
    u32 excl = s - v + (wv ? wsum[wv-1] : 0u);
    wst[b*(NBK+1) + tid] = excl;
    cnt[tid] = excl;                      // cursor
    if (tid == 0) wst[b*(NBK+1) + NBK] = NDATA;
    __syncthreads();

    for (int p = tid; p < NDATA; p += 1024) {   // scatter (in-bucket order arbitrary)
        float x = bx[p*3], y = bx[p*3+1], z = bx[p*3+2];
        u32 pos = atomicAdd(&cnt[key2(x, y)], 1u);
        wp[(size_t)b*NDATA + pos] = make_float4(x, y, z, __uint_as_float((u32)p));
    }
}

// ---- K2: 2D-windowed scan + verified selection + vectorized fused epilogue --
__global__ __launch_bounds__(256, 8)
void grouping_kernel(const float* __restrict__ new_xyz,
                     const float* __restrict__ xyz,
                     const float* __restrict__ points,
                     const float4* __restrict__ wp, const u32* __restrict__ wst,
                     float* __restrict__ out, float T)
{
    __shared__ float cand_s[QPB][MAXCAND];   // f32 sqrt(d2)
    __shared__ int   cand_i[QPB][MAXCAND];   // point index (tie-break key)
    __shared__ int   sel[QPB][NSAMPLE];
    __shared__ __align__(16) float st[QPB][8*ROWF];  // 8-row staging (536 f32/query)

    const int tid  = threadIdx.x;
    const int wv   = tid >> 6;
    const int lane = tid & 63;
    const int q    = blockIdx.x * QPB + wv;   // one query per wave
    const int b    = q >> 10;                 // batch

    if (lane < NSAMPLE) sel[wv][lane] = 0;    // safety net; overwritten below

    const float qx = new_xyz[q*3 + 0];
    const float qy = new_xyz[q*3 + 1];
    const float qz = new_xyz[q*3 + 2];
    const float*  bx = xyz + (size_t)b * NDATA * 3;
    const float4* cp = wp  + (size_t)b * NDATA;

    // (x,y)-window (margin 0.2005 >> any f32 rounding slop in the d2<T chain)
    const int bxlo = cbucket(__fsub_rn(qx, 0.2005f));
    const int bxhi = cbucket(__fadd_rn(qx, 0.2005f));
    const int bylo = cbucket(__fsub_rn(qy, 0.2005f));
    const int byhi = cbucket(__fadd_rn(qy, 0.2005f));
    const u32* ws = wst + b*(NBK+1);

    // per x-column, the y-window is one contiguous segment of the sorted array
    int n = 0;                                // wave-uniform candidate count
    for (int c = bxlo; c <= bxhi; ++c) {
        const u32 j0 = ws[c*NBY + bylo];
        const u32 j1 = ws[c*NBY + byhi + 1];  // (c*NBY+byhi+1) <= NBK, sentinel ok
        for (u32 jb = j0; jb < j1; jb += 64) {
            u32 j  = jb + lane;
            bool in = j < j1;
            u32 jj = in ? j : (j1 - 1u);      // safe: loop body implies j1 >= 1
            float4 vv = cp[jj];
            // exact np f32 semantics: no FMA, left-to-right sum
            float dx = __fsub_rn(vv.x, qx);
            float dy = __fsub_rn(vv.y, qy);
            float dz = __fsub_rn(vv.z, qz);
            float d2 = __fadd_rn(__fadd_rn(__fmul_rn(dx,dx), __fmul_rn(dy,dy)),
                                 __fmul_rn(dz,dz));
            bool cc = in && (d2 < T);         // == sqrtf(d2) < 0.2f (monotone)
            u64 m = __ballot(cc);
            if (cc) {
                int pos = n + lanes_below(m);
                if (pos < MAXCAND) {
                    cand_s[wv][pos] = __fsqrt_rn(d2);   // ref sorts the f32 norm
                    cand_i[wv][pos] = (int)__float_as_uint(vv.w);
                }
            }
            n += (int)__popcll(m);
        }
    }

    // ---- rare pass: argmin for empty-ball queries (R18-verified form) ----
    int mini = 0;
    if (n == 0) {
        float mind = 3.402823466e38f; int mi = 0;
        for (int k = 0; k < NDATA/64; ++k) {
            int i = (k << 6) + lane;
            float dx = __fsub_rn(bx[i*3+0], qx);
            float dy = __fsub_rn(bx[i*3+1], qy);
            float dz = __fsub_rn(bx[i*3+2], qz);
            float d2 = __fadd_rn(__fadd_rn(__fmul_rn(dx,dx), __fmul_rn(dy,dy)),
                                 __fmul_rn(dz,dz));
            if (d2 < mind) { mind = d2; mi = i; }   // strict <: lowest idx per lane
        }
        float ms = __fsqrt_rn(mind);                // np tie rule on sqrt values
        for (int off = 32; off; off >>= 1) {
            float os = __shfl_xor(ms, off);
            int   oi = __shfl_xor(mi, off);
            if (os < ms || (os == ms && oi < mi)) { ms = os; mi = oi; }
        }
        mini = mi;
    }

    __syncthreads();   // block-uniform (loops above have no barriers)

    // ---- rank-place: (dist, point-index) lex == np stable argsort ----
    const int nj = n > MAXCAND ? MAXCAND : n;
    for (int kk = lane; kk < nj; kk += 64) {
        float sk = cand_s[wv][kk];
        int   ik = cand_i[wv][kk];
        int r = 0;
        for (int mm = 0; mm < nj; ++mm) {           // broadcast LDS reads
            float sm = cand_s[wv][mm];
            int   im = cand_i[wv][mm];
            r += (int)((sm < sk) | ((sm == sk) & (im < ik)));
        }
        if (r < NSAMPLE) sel[wv][r] = clampidx(ik);
    }
    __syncthreads();
    {
        const int nsel = nj < NSAMPLE ? nj : NSAMPLE;
        if (lane >= nsel && lane < NSAMPLE) {
            int pad = (nj > 0) ? sel[wv][0] : clampidx(mini);   // sorted_idx[0]
            sel[wv][lane] = pad;
        }
    }
    __syncthreads();

    // ---- outputs: f32 stores, values pre-rounded through bf16 ----
    // idx (chunk 1)
    if (lane < NSAMPLE)
        out[OUT_IDX + (size_t)q*NSAMPLE + lane] = rnbf((float)sel[wv][lane]);

    // grouped_xyz (chunk 2)
    for (int e = lane; e < NSAMPLE*3; e += 64) {
        int sR = e / 3, c2 = e - sR*3;
        int is = sel[wv][sR];
        out[OUT_GX + (size_t)q*(NSAMPLE*3) + e] = rnbf(bx[is*3 + c2]);
    }

    // new_points (chunk 0): 4 groups of 8 rows.
    //   gather: 16 lanes x float4 cover one 64-feat row (16B-aligned loads),
    //           4 rows per pass, 2 passes; xyz by lanes 0..23.
    //   store:  row-block is contiguous & 16B-aligned in out -> float4 stores.
    const float* prow = points + (size_t)b * NDATA * CFEAT;
    float* onp = out + (size_t)q * (NSAMPLE*ROWF);
    const int gq = lane >> 4;     // 0..3: row within gather pass
    const int lq = lane & 15;     // 0..15: float4 within the 64-feature row
    for (int g = 0; g < 4; ++g) {
        #pragma unroll
        for (int p = 0; p < 2; ++p) {
            int rl = p*4 + gq;                     // local row 0..7
            int is = sel[wv][g*8 + rl];
            const float4 v = *reinterpret_cast<const float4*>(
                                 prow + (size_t)is*CFEAT + 4*lq);
            float* d = &st[wv][rl*ROWF + 3 + 4*lq];
            d[0] = rnbf(v.x); d[1] = rnbf(v.y); d[2] = rnbf(v.z); d[3] = rnbf(v.w);
        }
        if (lane < 24) {                           // 8 rows x 3 xyz
            int rl = lane / 3, c = lane - rl*3;
            int is = sel[wv][g*8 + rl];
            st[wv][rl*ROWF + c] = rnbf(bx[(size_t)is*3 + c]);
        }
        __syncthreads();
        for (int i = lane; i < 134; i += 64) {     // 536 floats = 134 float4
            float4 t = *reinterpret_cast<const float4*>(&st[wv][4*i]);
            *reinterpret_cast<float4*>(onp + (size_t)g*536 + 4*i) = t;
        }
        __syncthreads();
    }
}

extern "C" void kernel_launch(void* const* d_in, const int* in_sizes, int n_in,
                              void* d_out, int out_size, void* d_ws, size_t ws_size,
                              hipStream_t stream) {
    // T = smallest f32 x with sqrtf(x) >= 0.2f  =>  (d2 < T) == (sqrtf(d2) < 0.2f)
    union { u32 u; float f; } lo, hi, mid;
    lo.u = 0u; hi.f = 0.05f;
    while (hi.u - lo.u > 1u) {
        mid.u = lo.u + (hi.u - lo.u) / 2u;
        if (sqrtf(mid.f) >= 0.2f) hi.u = mid.u; else lo.u = mid.u;
    }
    float T = hi.f;

    // ws layout: wp (float4, 1 MB) | wst (u32 starts, 8*(1024+1) = ~32.8 KB)
    float4* wp  = (float4*)d_ws;
    u32*    wst = (u32*)(wp + (size_t)BATCH*NDATA);

    const float* nxz = (const float*)d_in[0];
    const float* xyz = (const float*)d_in[1];
    const float* pts = (const float*)d_in[2];

    bin_kernel<<<BATCH, 1024, 0, stream>>>(xyz, wp, wst);
    grouping_kernel<<<(BATCH*NPOINT)/QPB, 256, 0, stream>>>(
        nxz, xyz, pts, wp, wst, (float*)d_out, T);
}